// Round 2
// baseline (1516.028 us; speedup 1.0000x reference)
//
#include <hip/hip_runtime.h>
#include <cstddef>

// WITRAN 2D PSGMU encoder, MI355X — v6: ONE persistent kernel for all 71
// steps, neighbor-local flag sync (no grid barrier, no cache flushes).
//
// Why: launch-per-step pays ~2us CP latency + an inter-dispatch L2
// invalidate per step, which evicts the read-only Wfrag/xall/Bp from the
// per-XCD L2 -> ~40 MB/step refetched from LLC. In a single persistent
// dispatch nothing is ever invalidated: W (208 KB per XCD, since blocks
// sharing kt land on XCD kt%8 under round-robin bid%8) stays L2-hot for
// all 71 steps.
//
// Coherence without flushes: the ONLY cross-block state is h (hf fp32 +
// hb fp16 ping-pong). All h accesses use relaxed AGENT-scope 8B atomics
// (= global_load/store sc0 sc1: write-through LLC, bypass L1/L2) — the
// same LLC round-trip h already paid at dispatch boundaries.
// Dependency analysis: block (mc,kt) at step s reads h rows [mc*48,+48)
// written at s-1 by chunks {mc-1, mc}; its writes at s touch rows
// [mc*48, +80) read at s-1 by chunks {mc, mc+1} (WAR on ping-pong).
// => wait on 3 per-mc counters: mc-1, mc, mc+1 of step s-1.
// Release: __syncthreads() (drains vmcnt on every wave) + relaxed
// fetch_add. Poll: relaxed atomic loads + s_sleep + bail-out guard
// (bug => wrong answer, never a hang).
// GEMM/update numerics identical to v5 (fp16 MFMA 16x16x32, fp32 carry).

namespace {
constexpr int H_   = 256;
constexpr int C_   = 32;
constexpr int B_   = 32;
constexpr int R_   = 24;
constexpr int LOR_ = 48;
constexpr int L_   = 71;
constexpr int N_   = 768;
constexpr int KH_  = 512;
constexpr int KT_  = 544;
constexpr int AST_ = 552;   // LDS A stride (elems)
}

typedef __attribute__((ext_vector_type(8))) _Float16       f16x8;
typedef __attribute__((ext_vector_type(8))) unsigned short u16x8;
typedef __attribute__((ext_vector_type(4))) float          f32x4;
typedef __attribute__((ext_vector_type(2))) float          f32x2;

__device__ __forceinline__ float fsig(float x)  { return 1.f / (1.f + __expf(-x)); }
__device__ __forceinline__ float ftanhf(float x){ float e = __expf(2.f * x); return 1.f - 2.f / (e + 1.f); }

__device__ __forceinline__ unsigned long long ld_agent64(const void* p) {
    return __hip_atomic_load((const unsigned long long*)p,
                             __ATOMIC_RELAXED, __HIP_MEMORY_SCOPE_AGENT);
}
__device__ __forceinline__ void st_agent64(void* p, unsigned long long v) {
    __hip_atomic_store((unsigned long long*)p, v,
                       __ATOMIC_RELAXED, __HIP_MEMORY_SCOPE_AGENT);
}

// ---------------------------------------------------------------------------
// Prep 1: W -> fragment-native fp16 (verified layout).
// Wfrag[((kc*96 + lt)*64 + lane)*8 + j8]; lt=kt*6+g; col j=g*256+kt*16+kl
// ---------------------------------------------------------------------------
__global__ __launch_bounds__(256) void prep_w(const float* __restrict__ W,
                                              _Float16* __restrict__ Wfrag) {
    int o = blockIdx.x * 256 + threadIdx.x;          // < 835,584
    int j8   = o & 7;
    int lane = (o >> 3) & 63;
    int rest = o >> 9;
    int lt   = rest % 96;
    int kc   = rest / 96;                            // < 17
    int n0 = lane & 15, quad = lane >> 4;
    int lg  = lt * 16 + n0;
    int kt  = lg / 96;
    int rem = lg % 96;
    int g  = rem >> 4, kl = rem & 15;
    int j  = g * 256 + kt * 16 + kl;
    int kg = kc * 32 + quad * 8 + j8;
    Wfrag[o] = (_Float16)W[j * KT_ + kg];
}

// ---------------------------------------------------------------------------
// Prep 2: all shifted x slices, fp16. xall[s][n][c], n=r*32+b, l=s-r.
// ---------------------------------------------------------------------------
__global__ __launch_bounds__(256) void prep_x(const float* __restrict__ inp,
                                              _Float16* __restrict__ xall) {
    int o = blockIdx.x * 256 + threadIdx.x;          // < 1,744,896
    int c = o & 31;
    int n = (o >> 5) % N_;
    int s = (o >> 5) / N_;
    int r = n >> 5, b = n & 31;
    int l = s - r;
    float v = 0.f;
    if (l >= 0 && l < LOR_) v = inp[((b * LOR_ + l) * R_ + r) * C_ + c];
    xall[o] = (_Float16)v;
}

// ---------------------------------------------------------------------------
// Persistent kernel: 256 blocks (1/CU), all 71 steps.
// kt = bx&15, mc = bx>>4; 6 waves, wave = gate group g.
// ---------------------------------------------------------------------------
__global__ __launch_bounds__(384, 2) void steps_all(
    const _Float16* __restrict__ Wfrag,
    const _Float16* __restrict__ xall,
    _Float16* __restrict__ hb0, _Float16* __restrict__ hb1,
    float*    __restrict__ hf0, float*    __restrict__ hf1,
    const float* __restrict__ Bp,
    float* __restrict__ out0, float* __restrict__ out1, float* __restrict__ out2,
    unsigned int* __restrict__ cnt)
{
    __shared__ unsigned short As[48 * AST_];   // A tile: 48 x 544 (pad 552)
    __shared__ float Gt[48][104];              // gate tile 48m x 96l

    const int t    = threadIdx.x;
    const int wv   = t >> 6;                   // 0..5 = gate group g
    const int lane = t & 63;
    const int n0   = lane & 15;
    const int quad = lane >> 4;
    const int kt   = blockIdx.x & 15;
    const int mc   = blockIdx.x >> 4;
    const int mcm  = (mc + 15) & 15;
    const int mcp  = (mc + 1) & 15;

    for (int s = 0; s < L_; ++s) {
        // ---- wait for step s-1 of chunks {mc-1, mc, mc+1} -------------------
        if (s > 0) {
            if (t == 0) {
                const unsigned base = (unsigned)(s - 1) * 16u;
                int guard = 0;
                for (;;) {
                    unsigned a = __hip_atomic_load(cnt + base + mcm, __ATOMIC_RELAXED, __HIP_MEMORY_SCOPE_AGENT);
                    unsigned b = __hip_atomic_load(cnt + base + mc , __ATOMIC_RELAXED, __HIP_MEMORY_SCOPE_AGENT);
                    unsigned c = __hip_atomic_load(cnt + base + mcp, __ATOMIC_RELAXED, __HIP_MEMORY_SCOPE_AGENT);
                    if (a >= 16u && b >= 16u && c >= 16u) break;
                    __builtin_amdgcn_s_sleep(1);
                    if (++guard > (1 << 24)) break;   // bug => wrong answer, not hang
                }
            }
            __syncthreads();
        }

        const _Float16* hbc = (s & 1) ? hb1 : hb0;
        _Float16*       hbn = (s & 1) ? hb0 : hb1;
        const float*    hfc = (s & 1) ? hf1 : hf0;
        float*          hfn = (s & 1) ? hf0 : hf1;

        // ---- stage A: h 48x512 via agent 8B loads (LLC), x plain ------------
#pragma unroll
        for (int it = 0; it < 16; ++it) {
            int q   = it * 384 + t;            // < 6144 chunks of 4 halves
            int row = q >> 7;
            int c4  = (q & 127) * 4;
            unsigned long long v = ld_agent64(
                (const unsigned short*)hbc + (size_t)(mc * 48 + row) * KH_ + c4);
            *(unsigned long long*)(void*)(&As[row * AST_ + c4]) = v;
        }
        if (t < 192) {
            int row = t >> 2;
            int col = (t & 3) * 8;
            *(u16x8*)(void*)(&As[row * AST_ + 512 + col]) =
                *(const u16x8*)(const void*)((const unsigned short*)xall +
                                             (size_t)(s * N_ + mc * 48 + row) * C_ + col);
        }
        __syncthreads();

        // ---- GEMM: wave = gate g, 3 m-tiles x 16 gate cols ------------------
        f32x4 acc[3];
#pragma unroll
        for (int mt = 0; mt < 3; ++mt) acc[mt] = (f32x4){0.f, 0.f, 0.f, 0.f};

#pragma unroll
        for (int kc = 0; kc < 17; ++kc) {
            f16x8 b = *(const f16x8*)(const void*)(
                Wfrag + ((size_t)(kc * 96 + kt * 6 + wv) * 64 + lane) * 8);
            f16x8 a[3];
#pragma unroll
            for (int mt = 0; mt < 3; ++mt)
                a[mt] = *(const f16x8*)(const void*)(
                    &As[(mt * 16 + n0) * AST_ + kc * 32 + quad * 8]);
#pragma unroll
            for (int mt = 0; mt < 3; ++mt)
                acc[mt] = __builtin_amdgcn_mfma_f32_16x16x32_f16(a[mt], b, acc[mt], 0, 0, 0);
        }

        // D layout: col = lane&15 (gate col), row = quad*4 + reg (m)
#pragma unroll
        for (int mt = 0; mt < 3; ++mt)
#pragma unroll
            for (int reg = 0; reg < 4; ++reg)
                Gt[mt * 16 + quad * 4 + reg][wv * 16 + n0] = acc[mt][reg];

        __syncthreads();

        // ---- fused update: 48m x 16k, thread = 1 m-row x 2 k ----------------
        {
            const int mm = t >> 3;
            const int kp = (t & 7) * 2;
            const int n  = mc * 48 + mm;
            const int k  = kt * 16 + kp;
            const int r  = n >> 5, b = n & 31;
            const bool useb = (r <= s) && (s < R_);

            f32x2 gv[6];
#pragma unroll
            for (int g = 0; g < 6; ++g) {
                f32x2 v  = *(const f32x2*)(const void*)&Gt[mm][g * 16 + kp];
                f32x2 bp = *(const f32x2*)(const void*)(Bp + g * 256 + k);
                gv[g] = useb ? (v + bp) : v;
            }

            f32x2 hro = __builtin_bit_cast(f32x2, ld_agent64(hfc + (size_t)n * KH_ + k));
            f32x2 hco = __builtin_bit_cast(f32x2, ld_agent64(hfc + (size_t)n * KH_ + 256 + k));

            f32x2 hrv, hcv;
#pragma unroll
            for (int j = 0; j < 2; ++j) {
                float ur = fsig(gv[0][j]);
                float oR = fsig(gv[1][j]);
                float uc = fsig(gv[2][j]);
                float oc = fsig(gv[3][j]);
                float ir = ftanhf(gv[4][j]);
                float ic = ftanhf(gv[5][j]);
                hrv[j] = ftanhf((1.f - ur) * hro[j] + ur * ir) * oR;
                hcv[j] = ftanhf((1.f - uc) * hco[j] + uc * ic) * oc;
            }

            // trace output: single-writer, read post-kernel -> plain nt stores
            float* o0 = out0 + ((size_t)n * L_ + s) * 512;
            __builtin_nontemporal_store(hrv, (f32x2*)(void*)(o0 + k));
            __builtin_nontemporal_store(hcv, (f32x2*)(void*)(o0 + 256 + k));

            int n2 = n + B_; if (n2 >= N_) n2 -= N_;
            st_agent64(hfn + (size_t)n  * KH_ + k,       __builtin_bit_cast(unsigned long long, hrv));
            st_agent64(hfn + (size_t)n2 * KH_ + 256 + k, __builtin_bit_cast(unsigned long long, hcv));

            union { _Float16 h[2]; unsigned int u; } pr, pc;
            pr.h[0] = (_Float16)hrv[0]; pr.h[1] = (_Float16)hrv[1];
            pc.h[0] = (_Float16)hcv[0]; pc.h[1] = (_Float16)hcv[1];
            __hip_atomic_store((unsigned int*)(hbn + (size_t)n  * KH_ + k),       pr.u,
                               __ATOMIC_RELAXED, __HIP_MEMORY_SCOPE_AGENT);
            __hip_atomic_store((unsigned int*)(hbn + (size_t)n2 * KH_ + 256 + k), pc.u,
                               __ATOMIC_RELAXED, __HIP_MEMORY_SCOPE_AGENT);

            if (s >= LOR_ - 1 && r == s - (LOR_ - 1))
                __builtin_nontemporal_store(hrv, (f32x2*)(void*)(out2 + (size_t)(b * R_ + r) * H_ + k));
            if (r == R_ - 1 && s >= R_ - 1)
                __builtin_nontemporal_store(hcv, (f32x2*)(void*)(out1 + (size_t)(b * LOR_ + (s - (R_ - 1))) * H_ + k));
        }

        // ---- release: all waves drain (syncthreads waits vmcnt), then flag --
        __syncthreads();
        if (t == 0 && s + 1 < L_)
            __hip_atomic_fetch_add(cnt + (unsigned)s * 16u + mc, 1u,
                                   __ATOMIC_RELAXED, __HIP_MEMORY_SCOPE_AGENT);
    }
}

// ---------------------------------------------------------------------------
extern "C" void kernel_launch(void* const* d_in, const int* in_sizes, int n_in,
                              void* d_out, int out_size, void* d_ws, size_t ws_size,
                              hipStream_t stream) {
    const float* inp = (const float*)d_in[0];
    const float* W   = (const float*)d_in[1];
    const float* Bp  = (const float*)d_in[2];

    float* out0 = (float*)d_out;
    float* out1 = out0 + (size_t)N_ * L_ * 512;
    float* out2 = out1 + (size_t)B_ * LOR_ * H_;

    char* ws = (char*)d_ws;
    _Float16* Wfrag = (_Float16*)(ws);                 // 1,671,168 B
    _Float16* xall  = (_Float16*)(ws + 1671168);       // 3,489,792 B
    _Float16* hb0   = (_Float16*)(ws + 5160960);       //   786,432 B
    _Float16* hb1   = (_Float16*)(ws + 5947392);       //   786,432 B
    float*    hf0   = (float*)(ws + 6733824);          // 1,572,864 B
    float*    hf1   = (float*)(ws + 8306688);          // 1,572,864 B
    unsigned int* cnt = (unsigned int*)(ws + 9879552); //     4,544 B (71*16*4)

    (void)hipMemsetAsync(hb0, 0, 786432, stream);
    (void)hipMemsetAsync(hf0, 0, 1572864, stream);
    (void)hipMemsetAsync(cnt, 0, 4544, stream);

    prep_w<<<3264, 256, 0, stream>>>(W, Wfrag);
    prep_x<<<6816, 256, 0, stream>>>(inp, xall);

    steps_all<<<256, 384, 0, stream>>>(Wfrag, xall, hb0, hb1, hf0, hf1,
                                       Bp, out0, out1, out2, cnt);
}

// Round 3
// 687.770 us; speedup vs baseline: 2.2043x; 2.2043x over previous
//
#include <hip/hip_runtime.h>
#include <cstddef>

// WITRAN 2D PSGMU encoder, MI355X — v7: launch-per-step (persistent/software
// sync TWICE refuted: v6 flag-sync 20.4us/step, prior grid barrier 30-38us;
// CP launch+invalidate ~9us/step is the fastest barrier available), with
// intra-step overlap via 2 blocks/CU:
//   - grid 512 = 32 mc-chunks x 24 rows x 16 kt  (was 256 x 48-row chunks).
//     One block's GEMM overlaps the other's LLC stage / W-load stalls.
//     2nd MFMA m-tile is 1/3 padded (garbage rows are per-row independent,
//     never written); W L2 traffic 2x but L2-served and hidden.
//   - update-phase Bp/hf loads hoisted to kernel start (LDS-independent;
//     compiler can't hoist across barriers, so their LLC latency was
//     serially exposed after the 2nd barrier).
//   - Gt stride 104 -> 98: write-side LDS bank conflicts 4-way -> 2-way.
//   - prep_w + prep_x + h zero-init fused into ONE dispatch.
// fp16 MFMA 16x16x32, fp32 h carry + fp16 shadow (v5 numerics, absmax 9.8e-4).

namespace {
constexpr int H_   = 256;
constexpr int C_   = 32;
constexpr int B_   = 32;
constexpr int R_   = 24;
constexpr int LOR_ = 48;
constexpr int L_   = 71;
constexpr int N_   = 768;
constexpr int KH_  = 512;
constexpr int KT_  = 544;
constexpr int AST_ = 552;   // LDS A stride (elems)
constexpr int BM_  = 24;    // rows per block
}

typedef __attribute__((ext_vector_type(8))) _Float16       f16x8;
typedef __attribute__((ext_vector_type(8))) unsigned short u16x8;
typedef __attribute__((ext_vector_type(4))) float          f32x4;
typedef __attribute__((ext_vector_type(2))) float          f32x2;

__device__ __forceinline__ float fsig(float x)  { return 1.f / (1.f + __expf(-x)); }
__device__ __forceinline__ float ftanhf(float x){ float e = __expf(2.f * x); return 1.f - 2.f / (e + 1.f); }

// ---------------------------------------------------------------------------
// Fused prep: Wfrag build + x shift/convert + h zero-init, one dispatch.
// Wfrag[((kc*96 + lt)*64 + lane)*8 + j8]; lt=kt*6+g; col j=g*256+kt*16+kl
// ---------------------------------------------------------------------------
__global__ __launch_bounds__(256) void prep_all(const float* __restrict__ W,
                                                const float* __restrict__ inp,
                                                _Float16* __restrict__ Wfrag,
                                                _Float16* __restrict__ xall,
                                                unsigned long long* __restrict__ zb,
                                                unsigned long long* __restrict__ zf) {
    const int bx = blockIdx.x;
    const int t  = threadIdx.x;
    if (bx < 3264) {                                 // W -> fragment fp16
        int o = bx * 256 + t;                        // < 835,584
        int j8   = o & 7;
        int lane = (o >> 3) & 63;
        int rest = o >> 9;
        int lt   = rest % 96;
        int kc   = rest / 96;                        // < 17
        int n0 = lane & 15, quad = lane >> 4;
        int lg  = lt * 16 + n0;
        int kt  = lg / 96;
        int rem = lg % 96;
        int g  = rem >> 4, kl = rem & 15;
        int j  = g * 256 + kt * 16 + kl;
        int kg = kc * 32 + quad * 8 + j8;
        Wfrag[o] = (_Float16)W[j * KT_ + kg];
    } else if (bx < 10080) {                         // shifted x slices, fp16
        int o = (bx - 3264) * 256 + t;               // < 1,744,896
        int c = o & 31;
        int n = (o >> 5) % N_;
        int s = (o >> 5) / N_;
        int r = n >> 5, b = n & 31;
        int l = s - r;
        float v = 0.f;
        if (l >= 0 && l < LOR_) v = inp[((b * LOR_ + l) * R_ + r) * C_ + c];
        xall[o] = (_Float16)v;
    } else if (bx < 10464) {                         // zero hb0 (98,304 u64)
        zb[(bx - 10080) * 256 + t] = 0ull;
    } else {                                         // zero hf0 (196,608 u64)
        zf[(bx - 10464) * 256 + t] = 0ull;
    }
}

// ---------------------------------------------------------------------------
// One step. 512 blocks: kt = bx&15, mc = bx>>4 (rows [mc*24, mc*24+24)).
// 6 waves, wave wv = gate group g. 2 blocks/CU (LDS 44.7 KB, VGPR<=170).
// ---------------------------------------------------------------------------
__global__ __launch_bounds__(384, 3) void step_k(
    const _Float16* __restrict__ Wfrag,
    const _Float16* __restrict__ xall,
    const _Float16* __restrict__ hbc,
    const float*    __restrict__ hfc,
    _Float16*       __restrict__ hbn,
    float*          __restrict__ hfn,
    const float* __restrict__ Bp,
    float* __restrict__ out0, float* __restrict__ out1, float* __restrict__ out2,
    int s)
{
    __shared__ unsigned short As[32 * AST_];   // 24 valid rows + 8 pad (MFMA tile)
    __shared__ float Gt[24][98];               // gate tile 24m x 96l, 2-way banks

    const int t    = threadIdx.x;
    const int wv   = t >> 6;                   // 0..5 = gate group g
    const int lane = t & 63;
    const int n0   = lane & 15;
    const int quad = lane >> 4;
    const int kt   = blockIdx.x & 15;
    const int mc   = blockIdx.x >> 4;          // 0..31

    // ---- early independent loads for the update phase (waves 0-2) ----------
    const int mm = t >> 3;                     // row within chunk (t<192)
    const int kp = (t & 7) * 2;
    const int n  = mc * BM_ + mm;
    const int k  = kt * 16 + kp;
    f32x2 bp[6], hro, hco;
    if (t < 192) {
#pragma unroll
        for (int g = 0; g < 6; ++g)
            bp[g] = *(const f32x2*)(const void*)(Bp + g * 256 + k);
        hro = *(const f32x2*)(const void*)(hfc + (size_t)n * KH_ + k);
        hco = *(const f32x2*)(const void*)(hfc + (size_t)n * KH_ + 256 + k);
    }

    // ---- stage A (h 24x512 + x 24x32) into LDS ------------------------------
#pragma unroll
    for (int it = 0; it < 4; ++it) {
        int q   = it * 384 + t;                // < 1536
        int row = q >> 6;
        int col = (q & 63) * 8;
        *(u16x8*)(void*)(&As[row * AST_ + col]) =
            *(const u16x8*)(const void*)((const unsigned short*)hbc +
                                         (size_t)(mc * BM_ + row) * KH_ + col);
    }
    if (t < 96) {
        int row = t >> 2;
        int col = (t & 3) * 8;
        *(u16x8*)(void*)(&As[row * AST_ + 512 + col]) =
            *(const u16x8*)(const void*)((const unsigned short*)xall +
                                         (size_t)(s * N_ + mc * BM_ + row) * C_ + col);
    }
    __syncthreads();

    // ---- GEMM: wave = gate g, 2 m-tiles (2nd 1/3 padded) x 16 gate cols -----
    f32x4 acc0 = (f32x4){0.f, 0.f, 0.f, 0.f};
    f32x4 acc1 = (f32x4){0.f, 0.f, 0.f, 0.f};

#pragma unroll
    for (int kc = 0; kc < 17; ++kc) {
        f16x8 b = *(const f16x8*)(const void*)(
            Wfrag + ((size_t)(kc * 96 + kt * 6 + wv) * 64 + lane) * 8);
        f16x8 a0 = *(const f16x8*)(const void*)(
            &As[(n0) * AST_ + kc * 32 + quad * 8]);
        f16x8 a1 = *(const f16x8*)(const void*)(
            &As[(16 + n0) * AST_ + kc * 32 + quad * 8]);
        acc0 = __builtin_amdgcn_mfma_f32_16x16x32_f16(a0, b, acc0, 0, 0, 0);
        acc1 = __builtin_amdgcn_mfma_f32_16x16x32_f16(a1, b, acc1, 0, 0, 0);
    }

    // D layout: col = lane&15 (gate col), row = quad*4 + reg (m)
#pragma unroll
    for (int reg = 0; reg < 4; ++reg)
        Gt[quad * 4 + reg][wv * 16 + n0] = acc0[reg];
    if (quad < 2) {
#pragma unroll
        for (int reg = 0; reg < 4; ++reg)
            Gt[16 + quad * 4 + reg][wv * 16 + n0] = acc1[reg];
    }

    __syncthreads();

    // ---- fused update: 24m x 16k, thread = 1 m-row x 2 k (waves 0-2) --------
    if (t < 192) {
        const int r  = n >> 5, b = n & 31;
        const bool useb = (r <= s) && (s < R_);

        f32x2 gv[6];
#pragma unroll
        for (int g = 0; g < 6; ++g) {
            f32x2 v = *(const f32x2*)(const void*)&Gt[mm][g * 16 + kp];
            gv[g] = useb ? (v + bp[g]) : v;
        }

        f32x2 hrv, hcv;
#pragma unroll
        for (int j = 0; j < 2; ++j) {
            float ur = fsig(gv[0][j]);
            float oR = fsig(gv[1][j]);
            float uc = fsig(gv[2][j]);
            float oc = fsig(gv[3][j]);
            float ir = ftanhf(gv[4][j]);
            float ic = ftanhf(gv[5][j]);
            hrv[j] = ftanhf((1.f - ur) * hro[j] + ur * ir) * oR;
            hcv[j] = ftanhf((1.f - uc) * hco[j] + uc * ic) * oc;
        }

        // trace output (write-only: non-temporal, keep L2 clean for W/h)
        float* o0 = out0 + ((size_t)n * L_ + s) * 512;
        __builtin_nontemporal_store(hrv, (f32x2*)(void*)(o0 + k));
        __builtin_nontemporal_store(hcv, (f32x2*)(void*)(o0 + 256 + k));

        int n2 = n + B_; if (n2 >= N_) n2 -= N_;
        *(f32x2*)(void*)(hfn + (size_t)n  * KH_ + k)       = hrv;
        *(f32x2*)(void*)(hfn + (size_t)n2 * KH_ + 256 + k) = hcv;

        _Float16* pr = hbn + (size_t)n  * KH_ + k;
        _Float16* pc = hbn + (size_t)n2 * KH_ + 256 + k;
        pr[0] = (_Float16)hrv[0]; pr[1] = (_Float16)hrv[1];
        pc[0] = (_Float16)hcv[0]; pc[1] = (_Float16)hcv[1];

        if (s >= LOR_ - 1 && r == s - (LOR_ - 1))
            __builtin_nontemporal_store(hrv, (f32x2*)(void*)(out2 + (size_t)(b * R_ + r) * H_ + k));
        if (r == R_ - 1 && s >= R_ - 1)
            __builtin_nontemporal_store(hcv, (f32x2*)(void*)(out1 + (size_t)(b * LOR_ + (s - (R_ - 1))) * H_ + k));
    }
}

// ---------------------------------------------------------------------------
extern "C" void kernel_launch(void* const* d_in, const int* in_sizes, int n_in,
                              void* d_out, int out_size, void* d_ws, size_t ws_size,
                              hipStream_t stream) {
    const float* inp = (const float*)d_in[0];
    const float* W   = (const float*)d_in[1];
    const float* Bp  = (const float*)d_in[2];

    float* out0 = (float*)d_out;
    float* out1 = out0 + (size_t)N_ * L_ * 512;
    float* out2 = out1 + (size_t)B_ * LOR_ * H_;

    char* ws = (char*)d_ws;
    _Float16* Wfrag = (_Float16*)(ws);                 // 1,671,168 B
    _Float16* xall  = (_Float16*)(ws + 1671168);       // 3,489,792 B
    _Float16* hb0   = (_Float16*)(ws + 5160960);       //   786,432 B
    _Float16* hb1   = (_Float16*)(ws + 5947392);       //   786,432 B
    float*    hf0   = (float*)(ws + 6733824);          // 1,572,864 B
    float*    hf1   = (float*)(ws + 8306688);          // 1,572,864 B

    prep_all<<<11232, 256, 0, stream>>>(W, inp, Wfrag, xall,
                                        (unsigned long long*)hb0,
                                        (unsigned long long*)hf0);

    for (int s = 0; s < L_; ++s) {
        const _Float16* hbc = (s & 1) ? hb1 : hb0;
        _Float16*       hbn = (s & 1) ? hb0 : hb1;
        const float*    hfc = (s & 1) ? hf1 : hf0;
        float*          hfn = (s & 1) ? hf0 : hf1;
        step_k<<<512, 384, 0, stream>>>(Wfrag, xall, hbc, hfc, hbn, hfn,
                                        Bp, out0, out1, out2, s);
    }
}

// Round 4
// 629.426 us; speedup vs baseline: 2.4086x; 1.0927x over previous
//
#include <hip/hip_runtime.h>
#include <cstddef>

// WITRAN 2D PSGMU encoder, MI355X — v8: v5 tiling (BM=48, 256 blocks, no
// padded MFMA tiles — v7's BM=24 cost +33% MFMA for nothing) plus:
//  1. Register W-prefetch: all 17 Wfrag fragments loaded into VGPRs BEFORE
//     the stage phase, so their post-invalidate LLC latency overlaps the
//     h-staging instead of serializing inside the GEMM loop (1 block/CU =
//     no other waves to hide behind).
//  2. fp16-only h carry: update reads h_old straight from the staged LDS
//     tile (As). Removes the hf fp32 buffer entirely: -1.57 MB read,
//     -1.57 MB store, -1.57 MB end-of-kernel L2 writeback per step.
//     Accuracy: one extra fp16 quantization into a contractive recurrence;
//     predicted absmax ~1.5e-3 (v4 passed at 1.95e-3).
//  3. Packed u32 h stores; Bp loads gated on s<R; fused prep dispatch.
// Launch-per-step retained (software sync twice refuted: v6 flag-sync
// 20.4us/step, earlier grid barrier 30-38us/step).

namespace {
constexpr int H_   = 256;
constexpr int C_   = 32;
constexpr int B_   = 32;
constexpr int R_   = 24;
constexpr int LOR_ = 48;
constexpr int L_   = 71;
constexpr int N_   = 768;
constexpr int KH_  = 512;
constexpr int KT_  = 544;
constexpr int AST_ = 552;   // LDS A stride (elems)
}

typedef __attribute__((ext_vector_type(8))) _Float16       f16x8;
typedef __attribute__((ext_vector_type(8))) unsigned short u16x8;
typedef __attribute__((ext_vector_type(4))) float          f32x4;
typedef __attribute__((ext_vector_type(2))) float          f32x2;

__device__ __forceinline__ float fsig(float x)  { return 1.f / (1.f + __expf(-x)); }
__device__ __forceinline__ float ftanhf(float x){ float e = __expf(2.f * x); return 1.f - 2.f / (e + 1.f); }

// ---------------------------------------------------------------------------
// Fused prep: Wfrag build + x shift/convert + hb zero-init, one dispatch.
// Wfrag[((kc*96 + lt)*64 + lane)*8 + j8]; lt=kt*6+g; col j=g*256+kt*16+kl
// ---------------------------------------------------------------------------
__global__ __launch_bounds__(256) void prep_all(const float* __restrict__ W,
                                                const float* __restrict__ inp,
                                                _Float16* __restrict__ Wfrag,
                                                _Float16* __restrict__ xall,
                                                unsigned long long* __restrict__ zb) {
    const int bx = blockIdx.x;
    const int t  = threadIdx.x;
    if (bx < 3264) {                                 // W -> fragment fp16
        int o = bx * 256 + t;                        // < 835,584
        int j8   = o & 7;
        int lane = (o >> 3) & 63;
        int rest = o >> 9;
        int lt   = rest % 96;
        int kc   = rest / 96;                        // < 17
        int n0 = lane & 15, quad = lane >> 4;
        int lg  = lt * 16 + n0;
        int kt  = lg / 96;
        int rem = lg % 96;
        int g  = rem >> 4, kl = rem & 15;
        int j  = g * 256 + kt * 16 + kl;
        int kg = kc * 32 + quad * 8 + j8;
        Wfrag[o] = (_Float16)W[j * KT_ + kg];
    } else if (bx < 10080) {                         // shifted x slices, fp16
        int o = (bx - 3264) * 256 + t;               // < 1,744,896
        int c = o & 31;
        int n = (o >> 5) % N_;
        int s = (o >> 5) / N_;
        int r = n >> 5, b = n & 31;
        int l = s - r;
        float v = 0.f;
        if (l >= 0 && l < LOR_) v = inp[((b * LOR_ + l) * R_ + r) * C_ + c];
        xall[o] = (_Float16)v;
    } else {                                         // zero hb0 (98,304 u64)
        zb[(bx - 10080) * 256 + t] = 0ull;
    }
}

// ---------------------------------------------------------------------------
// One step. 256 blocks: kt = bx&15, mc = bx>>4 (rows [mc*48, +48)).
// 6 waves, wave wv = gate group g. 1 block/CU.
// ---------------------------------------------------------------------------
__global__ __launch_bounds__(384, 2) void step_k(
    const _Float16* __restrict__ Wfrag,
    const _Float16* __restrict__ xall,
    const _Float16* __restrict__ hbc,
    _Float16*       __restrict__ hbn,
    const float* __restrict__ Bp,
    float* __restrict__ out0, float* __restrict__ out1, float* __restrict__ out2,
    int s)
{
    __shared__ unsigned short As[48 * AST_];   // A tile: 48 x 544 (pad 552)
    __shared__ float Gt[48][98];               // gate tile 48m x 96l

    const int t    = threadIdx.x;
    const int wv   = t >> 6;                   // 0..5 = gate group g
    const int lane = t & 63;
    const int n0   = lane & 15;
    const int quad = lane >> 4;
    const int kt   = blockIdx.x & 15;
    const int mc   = blockIdx.x >> 4;

    // ---- W prefetch: all 17 fragments issued before staging -----------------
    // LDS-independent; their post-invalidate LLC latency overlaps the stage.
    f16x8 bfr[17];
#pragma unroll
    for (int kc = 0; kc < 17; ++kc)
        bfr[kc] = *(const f16x8*)(const void*)(
            Wfrag + ((size_t)(kc * 96 + kt * 6 + wv) * 64 + lane) * 8);

    // ---- early Bp loads (only steps that use the bias) ----------------------
    const int mm = t >> 3;                     // update row (0..47)
    const int kp = (t & 7) * 2;
    const int n  = mc * 48 + mm;
    const int k  = kt * 16 + kp;
    f32x2 bp[6];
    if (s < R_) {
#pragma unroll
        for (int g = 0; g < 6; ++g)
            bp[g] = *(const f32x2*)(const void*)(Bp + g * 256 + k);
    }

    // ---- stage A (h 48x512 + x 48x32) into LDS ------------------------------
#pragma unroll
    for (int it = 0; it < 8; ++it) {
        int q   = it * 384 + t;                // < 3072
        int row = q >> 6;
        int col = (q & 63) * 8;
        *(u16x8*)(void*)(&As[row * AST_ + col]) =
            *(const u16x8*)(const void*)((const unsigned short*)hbc +
                                         (size_t)(mc * 48 + row) * KH_ + col);
    }
    if (t < 192) {
        int row = t >> 2;
        int col = (t & 3) * 8;
        *(u16x8*)(void*)(&As[row * AST_ + 512 + col]) =
            *(const u16x8*)(const void*)((const unsigned short*)xall +
                                         (size_t)(s * N_ + mc * 48 + row) * C_ + col);
    }
    __syncthreads();

    // ---- GEMM: wave = gate g, 3 m-tiles x 16 gate cols, W from registers ----
    f32x4 acc[3];
#pragma unroll
    for (int mt = 0; mt < 3; ++mt) acc[mt] = (f32x4){0.f, 0.f, 0.f, 0.f};

#pragma unroll
    for (int kc = 0; kc < 17; ++kc) {
        f16x8 a[3];
#pragma unroll
        for (int mt = 0; mt < 3; ++mt)
            a[mt] = *(const f16x8*)(const void*)(
                &As[(mt * 16 + n0) * AST_ + kc * 32 + quad * 8]);
#pragma unroll
        for (int mt = 0; mt < 3; ++mt)
            acc[mt] = __builtin_amdgcn_mfma_f32_16x16x32_f16(a[mt], bfr[kc], acc[mt], 0, 0, 0);
    }

    // D layout: col = lane&15 (gate col), row = quad*4 + reg (m)
#pragma unroll
    for (int mt = 0; mt < 3; ++mt)
#pragma unroll
        for (int reg = 0; reg < 4; ++reg)
            Gt[mt * 16 + quad * 4 + reg][wv * 16 + n0] = acc[mt][reg];

    __syncthreads();

    // ---- fused update: 48m x 16k, thread = 1 m-row x 2 k --------------------
    {
        const int r  = n >> 5, b = n & 31;
        const bool useb = (r <= s) && (s < R_);

        f32x2 gv[6];
#pragma unroll
        for (int g = 0; g < 6; ++g) {
            f32x2 v = *(const f32x2*)(const void*)&Gt[mm][g * 16 + kp];
            gv[g] = useb ? (v + bp[g]) : v;
        }

        // h_old straight from the staged LDS tile (fp16 carry)
        const _Float16* hrow = (const _Float16*)(const void*)&As[mm * AST_ + k];
        const _Float16* hcol = (const _Float16*)(const void*)&As[mm * AST_ + 256 + k];
        f32x2 hro = { (float)hrow[0], (float)hrow[1] };
        f32x2 hco = { (float)hcol[0], (float)hcol[1] };

        f32x2 hrv, hcv;
#pragma unroll
        for (int j = 0; j < 2; ++j) {
            float ur = fsig(gv[0][j]);
            float oR = fsig(gv[1][j]);
            float uc = fsig(gv[2][j]);
            float oc = fsig(gv[3][j]);
            float ir = ftanhf(gv[4][j]);
            float ic = ftanhf(gv[5][j]);
            hrv[j] = ftanhf((1.f - ur) * hro[j] + ur * ir) * oR;
            hcv[j] = ftanhf((1.f - uc) * hco[j] + uc * ic) * oc;
        }

        // trace output (write-only: non-temporal, keep L2 clean for W/h)
        float* o0 = out0 + ((size_t)n * L_ + s) * 512;
        __builtin_nontemporal_store(hrv, (f32x2*)(void*)(o0 + k));
        __builtin_nontemporal_store(hcv, (f32x2*)(void*)(o0 + 256 + k));

        int n2 = n + B_; if (n2 >= N_) n2 -= N_;

        union { _Float16 h[2]; unsigned int u; } pr, pc;
        pr.h[0] = (_Float16)hrv[0]; pr.h[1] = (_Float16)hrv[1];
        pc.h[0] = (_Float16)hcv[0]; pc.h[1] = (_Float16)hcv[1];
        *(unsigned int*)(void*)(hbn + (size_t)n  * KH_ + k)       = pr.u;
        *(unsigned int*)(void*)(hbn + (size_t)n2 * KH_ + 256 + k) = pc.u;

        if (s >= LOR_ - 1 && r == s - (LOR_ - 1))
            __builtin_nontemporal_store(hrv, (f32x2*)(void*)(out2 + (size_t)(b * R_ + r) * H_ + k));
        if (r == R_ - 1 && s >= R_ - 1)
            __builtin_nontemporal_store(hcv, (f32x2*)(void*)(out1 + (size_t)(b * LOR_ + (s - (R_ - 1))) * H_ + k));
    }
}

// ---------------------------------------------------------------------------
extern "C" void kernel_launch(void* const* d_in, const int* in_sizes, int n_in,
                              void* d_out, int out_size, void* d_ws, size_t ws_size,
                              hipStream_t stream) {
    const float* inp = (const float*)d_in[0];
    const float* W   = (const float*)d_in[1];
    const float* Bp  = (const float*)d_in[2];

    float* out0 = (float*)d_out;
    float* out1 = out0 + (size_t)N_ * L_ * 512;
    float* out2 = out1 + (size_t)B_ * LOR_ * H_;

    char* ws = (char*)d_ws;
    _Float16* Wfrag = (_Float16*)(ws);                 // 1,671,168 B
    _Float16* xall  = (_Float16*)(ws + 1671168);       // 3,489,792 B
    _Float16* hb0   = (_Float16*)(ws + 5160960);       //   786,432 B
    _Float16* hb1   = (_Float16*)(ws + 5947392);       //   786,432 B

    prep_all<<<10464, 256, 0, stream>>>(W, inp, Wfrag, xall,
                                        (unsigned long long*)hb0);

    for (int s = 0; s < L_; ++s) {
        const _Float16* hbc = (s & 1) ? hb1 : hb0;
        _Float16*       hbn = (s & 1) ? hb0 : hb1;
        step_k<<<256, 384, 0, stream>>>(Wfrag, xall, hbc, hbn,
                                        Bp, out0, out1, out2, s);
    }
}